// Round 20
// baseline (247.350 us; speedup 1.0000x reference)
//
#include <hip/hip_runtime.h>
#include <math.h>

#define HW 4096
#define CC 96
#define DD 192
#define NS 16
#define KK 4
#define LC 64
#define NC 64
#define NCH (8*DD*NS)   // 24576 chains
#define LOG2E 1.442695041f

__device__ __forceinline__ float siluf(float x){ return x / (1.f + __expf(-x)); }
__device__ __forceinline__ float softplus_fast(float x){ return (x > 20.f) ? x : __logf(1.f + __expf(x)); }

__device__ __forceinline__ int lmap_xs(int k, int l){
  if (k == 1) return ((l & 63) << 6) | (l >> 6);
  if (k == 2) return (HW - 1) - l;
  if (k == 3) { int r = (HW - 1) - l; return ((r & 63) << 6) | (r >> 6); }
  return l;
}

// K0: merged weight pre-transposes.
__global__ void k_prep(const float* __restrict__ cw, const float* __restrict__ xpw,
                       float* __restrict__ wT, float* __restrict__ xpwT){
  int o = blockIdx.x*256 + threadIdx.x;
  if (o < 165888){
    int co = o % 96; int rest = o / 96; int tap = rest % 9; int cig = rest / 9;
    wT[o] = cw[((size_t)co*192 + cig)*9 + tap];
  } else if (o < 165888 + 29184){
    int o2 = o - 165888;
    int c = o2 % 38; int rest = o2 / 38; int d = rest % 192; int k = rest / 192;
    xpwT[o2] = xpw[((size_t)(k*38 + c))*192 + d];
  }
}

// K1 v4 (best verified): conv3x3(192->96) partials, K-split 16 x 12ci.
__global__ void __launch_bounds__(256, 4)
k_conv1(const float* __restrict__ rgb, const float* __restrict__ tt,
        const float* __restrict__ wT, float* __restrict__ pbuf){
  __shared__ float in_lds[6][6][68];
  __shared__ __align__(16) float w_lds[6][9][64];
  int bi = blockIdx.x;
  int kc  = bi & 15;        int ci0 = kc*12;
  int cog = (bi >> 4) & 1;  int co0 = cog*48;
  int b   = (bi >> 5) & 1;
  int pt  = bi >> 6;        int h0 = pt*4;
  int tid = threadIdx.x;
  int pg = tid & 31;  int r = pg >> 3;  int w0 = (pg & 7)*8;
  int cg = tid >> 5;  int co_t = cg*6;

  float acc[6][8];
  #pragma unroll
  for (int c = 0; c < 6; ++c)
    #pragma unroll
    for (int p = 0; p < 8; ++p) acc[c][p] = 0.f;

  for (int s = 0; s < 2; ++s){
    if (s) __syncthreads();
    if (tid < 72){ int side = tid & 1; int rr = (tid % 12) >> 1; int ci = tid / 12;
                   in_lds[ci][rr][side ? 65 : 0] = 0.f; }
    for (int i = tid; i < 2304; i += 256){
      int ci = i / 384; int rem = i - ci*384; int rr = rem >> 6; int w = rem & 63;
      int grow = h0 - 1 + rr;
      int cig = ci0 + s*6 + ci;
      float v = 0.f;
      if (grow >= 0 && grow < 64){
        const float* src = (cig < CC) ? (rgb + (size_t)(b*CC+cig)*HW)
                                      : (tt  + (size_t)(b*CC+cig-CC)*HW);
        v = src[grow*64 + w];
      }
      in_lds[ci][rr][w+1] = v;
    }
    for (int i = tid; i < 2592; i += 256){
      int co = i % 48; int rest = i / 48; int tap = rest % 9; int ci = rest / 9;
      w_lds[ci][tap][(co/6)*8 + (co%6)] =
          wT[((size_t)(ci0 + s*6 + ci)*9 + tap)*96 + co0 + co];
    }
    __syncthreads();
    #pragma unroll
    for (int ci = 0; ci < 6; ++ci){
      float rowv[3][10];
      #pragma unroll
      for (int rr = 0; rr < 3; ++rr){
        const float* rp = &in_lds[ci][r+rr][w0];
        float4 a = *(const float4*)rp;
        float4 bb = *(const float4*)(rp+4);
        float2 cc = *(const float2*)(rp+8);
        rowv[rr][0]=a.x; rowv[rr][1]=a.y; rowv[rr][2]=a.z; rowv[rr][3]=a.w;
        rowv[rr][4]=bb.x; rowv[rr][5]=bb.y; rowv[rr][6]=bb.z; rowv[rr][7]=bb.w;
        rowv[rr][8]=cc.x; rowv[rr][9]=cc.y;
      }
      #pragma unroll
      for (int tap = 0; tap < 9; ++tap){
        int rt = tap/3, ct = tap - rt*3;
        float4 wa = *(const float4*)&w_lds[ci][tap][cg*8];
        float2 wb = *(const float2*)&w_lds[ci][tap][cg*8+4];
        float wv[6] = {wa.x, wa.y, wa.z, wa.w, wb.x, wb.y};
        #pragma unroll
        for (int p = 0; p < 8; ++p){
          float iv = rowv[rt][p + ct];
          #pragma unroll
          for (int c = 0; c < 6; ++c) acc[c][p] += wv[c]*iv;
        }
      }
    }
  }
  #pragma unroll
  for (int p = 0; p < 8; ++p){
    int pix = (h0 + r)*64 + w0 + p;
    float* o = pbuf + (((size_t)kc*2 + b)*HW + pix)*CC + co0 + co_t;
    float2 o0 = {acc[0][p], acc[1][p]};
    float2 o1 = {acc[2][p], acc[3][p]};
    float2 o2 = {acc[4][p], acc[5][p]};
    *(float2*)&o[0] = o0; *(float2*)&o[2] = o1; *(float2*)&o[4] = o2;
  }
}

// K1b: reduce 16 partials + bias + BN + ReLU + per-pixel LayerNorm -> xn (pixel-major)
__global__ void k_convred(const float* __restrict__ pbuf, const float* __restrict__ cb,
                          const float* __restrict__ bng, const float* __restrict__ bnb,
                          const float* __restrict__ bnm, const float* __restrict__ bnv,
                          const float* __restrict__ lng, const float* __restrict__ lnb,
                          float* __restrict__ xn){
  __shared__ float sm[4], sm2[4], smu[2], srs[2];
  int tid = threadIdx.x;
  int half = tid >> 7;
  int c = tid & 127;
  int pixg = blockIdx.x*2 + half;
  int b = pixg >> 12; int pix = pixg & (HW-1);
  float v = 0.f;
  if (c < CC){
    #pragma unroll
    for (int kc = 0; kc < 16; ++kc)
      v += pbuf[(((size_t)kc*2 + b)*HW + pix)*CC + c];
    v += cb[c];
    v = (v - bnm[c]) * rsqrtf(bnv[c] + 1e-5f);
    v = v * bng[c] + bnb[c];
    v = fmaxf(v, 0.f);
  }
  float s = v, s2 = v*v;
  #pragma unroll
  for (int off = 32; off; off >>= 1){ s += __shfl_down(s, off); s2 += __shfl_down(s2, off); }
  if ((tid & 63) == 0){ sm[tid>>6] = s; sm2[tid>>6] = s2; }
  __syncthreads();
  if (tid < 2){
    float ts = sm[2*tid] + sm[2*tid+1];
    float ts2 = sm2[2*tid] + sm2[2*tid+1];
    float mu = ts * (1.f/CC);
    float var = ts2 * (1.f/CC) - mu*mu;
    smu[tid] = mu; srs[tid] = rsqrtf(var + 1e-5f);
  }
  __syncthreads();
  if (c < CC)
    xn[(size_t)pixg*CC + c] = (v - smu[half])*srs[half]*lng[c] + lnb[c];
}

// K2b: xz(8192x384) = xn(8192x96) @ in_proj_w^T(96x384)
__global__ void k_inproj(const float* __restrict__ xn, const float* __restrict__ ipw,
                         float* __restrict__ xz){
  __shared__ float As[64][97];
  __shared__ __align__(16) float Bs[96][68];
  int p0 = blockIdx.x*64;
  int e0 = blockIdx.y*64;
  int tid = threadIdx.x;
  for (int idx = tid; idx < 64*96; idx += 256){
    int r = idx/96, c = idx - r*96;
    As[r][c] = xn[(size_t)(p0+r)*96 + c];
  }
  for (int idx = tid; idx < 96*64; idx += 256){
    int c = idx/64, e = idx - c*64;
    Bs[c][e] = ipw[(size_t)(e0+e)*96 + c];
  }
  __syncthreads();
  int tx = tid & 15, ty = tid >> 4;
  float acc[4][4] = {};
  for (int c = 0; c < 96; ++c){
    float a[4];
    #pragma unroll
    for (int i = 0; i < 4; ++i) a[i] = As[ty*4+i][c];
    float4 bb = *(const float4*)&Bs[c][tx*4];
    float bv[4] = {bb.x, bb.y, bb.z, bb.w};
    #pragma unroll
    for (int i = 0; i < 4; ++i)
      #pragma unroll
      for (int j = 0; j < 4; ++j) acc[i][j] += a[i]*bv[j];
  }
  for (int i = 0; i < 4; ++i){
    float4 o = {acc[i][0], acc[i][1], acc[i][2], acc[i][3]};
    *(float4*)&xz[(size_t)(p0+ty*4+i)*384 + e0 + tx*4] = o;
  }
}

// K3 v2: depthwise 3x3 conv + bias + SiLU -> xc (B, L, 192). Thread = 4 consecutive d.
__global__ void k_dwconv(const float* __restrict__ xz, const float* __restrict__ dww,
                         const float* __restrict__ dwb, float* __restrict__ xc){
  int gid = blockIdx.x*256 + threadIdx.x;    // 8192*48
  int dq = gid % 48; int bp = gid / 48;
  int d = dq*4;
  int pix = bp & (HW-1); int b = bp >> 12;
  int h = pix >> 6, w = pix & 63;
  float4 acc = *(const float4*)&dwb[d];
  float wreg[4][9];
  #pragma unroll
  for (int j = 0; j < 4; ++j)
    #pragma unroll
    for (int t = 0; t < 9; ++t) wreg[j][t] = dww[(d+j)*9 + t];
  #pragma unroll
  for (int dh = -1; dh <= 1; ++dh){
    int hh = h + dh;
    if (hh < 0 || hh > 63) continue;
    #pragma unroll
    for (int dw2 = -1; dw2 <= 1; ++dw2){
      int ww = w + dw2;
      if (ww < 0 || ww > 63) continue;
      float4 v = *(const float4*)&xz[((size_t)b*HW + hh*64 + ww)*384 + d];
      int t = (dh+1)*3 + (dw2+1);
      acc.x += v.x*wreg[0][t];
      acc.y += v.y*wreg[1][t];
      acc.z += v.z*wreg[2][t];
      acc.w += v.w*wreg[3][t];
    }
  }
  float4 o = {siluf(acc.x), siluf(acc.y), siluf(acc.z), siluf(acc.w)};
  *(float4*)&xc[(size_t)bp*DD + d] = o;
}

// K4 v6: x_dbl for a DIRECTION PAIR per block, 16-px tiles (1024 blocks).
__global__ void __launch_bounds__(320)
k_xdbl(const float* __restrict__ xc, const float* __restrict__ xpwT,
       const float* __restrict__ dtw, const float* __restrict__ dtb,
       float* __restrict__ Bsb, float* __restrict__ Csb, float* __restrict__ dlt){
  __shared__ float xs_t[48*20];      // [dd][j], 16 j + 4 pad
  __shared__ float w_t[48*80];       // [dd][c]: c<38 -> k=p, c>=38 -> k=p+2
  __shared__ float dts_s[2][16][8];
  int blk = blockIdx.x;              // b*512 + p*256 + lt
  int lt = blk & 255; int p = (blk >> 8) & 1; int b = blk >> 9;
  int l0 = lt*16;
  int tid = threadIdx.x;
  int lg = tid & 15, cg = tid >> 4;  // cg 0..19
  int c0 = cg*4;
  int b4kA = b*4 + p, b4kB = b*4 + p + 2;
  int wc = tid % 76;
  int wg = tid / 76;
  int kkW = (wc < 38) ? p : (p + 2);
  int ccW = (wc < 38) ? wc : wc - 38;

  float acc[4] = {0.f, 0.f, 0.f, 0.f};
  for (int ch = 0; ch < 4; ++ch){
    int d0 = ch*48;
    if (ch) __syncthreads();
    if (tid < 192){
      int j = tid & 15; int dq = tid >> 4;
      int l = l0 + j;
      int lm = (p == 0) ? l : (((l & 63) << 6) | (l >> 6));
      float4 v = *(const float4*)&xc[((size_t)b*HW + lm)*DD + d0 + dq*4];
      xs_t[(dq*4+0)*20 + j] = v.x;
      xs_t[(dq*4+1)*20 + j] = v.y;
      xs_t[(dq*4+2)*20 + j] = v.z;
      xs_t[(dq*4+3)*20 + j] = v.w;
    }
    if (wg < 4){
      #pragma unroll
      for (int dd = wg; dd < 48; dd += 4)
        w_t[dd*80 + wc] = xpwT[((size_t)kkW*192 + d0 + dd)*38 + ccW];
    }
    __syncthreads();
    #pragma unroll 4
    for (int dd = 0; dd < 48; ++dd){
      float4 wv = *(const float4*)&w_t[dd*80 + c0];
      float xv = xs_t[dd*20 + lg];
      acc[0] += wv.x*xv;
      acc[1] += wv.y*xv;
      acc[2] += wv.z*xv;
      acc[3] += wv.w*xv;
    }
  }
  {
    int lf = l0 + lg;
    int lr = HW - 1 - lf;
    #pragma unroll
    for (int j = 0; j < 4; ++j){
      int c = c0 + j;
      float v = acc[j];
      if      (c <  6) dts_s[0][lg][c] = v;
      else if (c < 22) Bsb [((size_t)b4kA*HW + lf)*NS + (c-6)]   = v;
      else if (c < 38) Csb [((size_t)b4kA*HW + lf)*NS + (c-22)]  = v;
      else if (c < 44) dts_s[1][lg][c-38] = v;
      else if (c < 60) Bsb [((size_t)b4kB*HW + lr)*NS + (c-44)]  = v;
      else if (c < 76) Csb [((size_t)b4kB*HW + lr)*NS + (c-60)]  = v;
    }
  }
  __syncthreads();

  for (int o = tid; o < 6144; o += 320){
    int dir = (o >= 3072) ? 1 : 0;
    int oo = o - dir*3072;
    int lj = oo / 192;
    int d  = oo - lj*192;
    int k  = dir ? (p + 2) : p;
    int b4k = dir ? b4kB : b4kA;
    int lout = dir ? (HW - 1 - (l0 + lj)) : (l0 + lj);
    const float* t = dts_s[dir][lj];
    const float* wp = &dtw[(size_t)(k*DD + d)*6];
    float s = dtb[k*DD + d] + t[0]*wp[0] + t[1]*wp[1] + t[2]*wp[2]
                            + t[3]*wp[3] + t[4]*wp[4] + t[5]*wp[5];
    dlt[((size_t)b4k*HW + lout)*DD + d] = softplus_fast(s);
  }
}

// K5a: per-chunk scan summaries. 4-lane n-split; Av pre-scaled by log2e -> exp2f.
__global__ void k_scan1(const float* __restrict__ dlt, const float* __restrict__ xc,
                        const float* __restrict__ Bsb, const float* __restrict__ Alog,
                        float* __restrict__ Ac, float* __restrict__ Bc){
  int tid = blockIdx.x*256 + threadIdx.x;
  int ng = tid & 3;
  int t2 = tid >> 2;
  int d = t2 % DD;
  int rest = t2 / DD;
  int chunk = rest & (NC-1);
  int b4k = rest >> 6;
  int k = b4k & 3, b = b4k >> 2;
  float4 Af = *(const float4*)&Alog[(size_t)(k*DD+d)*NS + ng*4];
  float Av[4] = {-__expf(Af.x)*LOG2E, -__expf(Af.y)*LOG2E,
                 -__expf(Af.z)*LOG2E, -__expf(Af.w)*LOG2E};
  float h[4] = {0.f,0.f,0.f,0.f};
  float ap[4] = {1.f,1.f,1.f,1.f};
  int l0 = chunk*LC;
  const float* dp  = dlt + ((size_t)b4k*HW + l0)*DD + d;
  const float4* Bp4 = (const float4*)(Bsb + ((size_t)b4k*HW + l0)*NS) + ng;
  const float* xcb = xc + (size_t)b*HW*DD + d;
  float dvc = dp[0];
  float xvc = xcb[(size_t)lmap_xs(k, l0)*DD];
  float4 Bvc = Bp4[0];
  #pragma unroll 4
  for (int i = 0; i < LC; ++i){
    float dvn = 0.f, xvn = 0.f; float4 Bvn = {0.f,0.f,0.f,0.f};
    if (i+1 < LC){
      dvn = dp[(size_t)(i+1)*DD];
      xvn = xcb[(size_t)lmap_xs(k, l0+i+1)*DD];
      Bvn = Bp4[(size_t)(i+1)*4];
    }
    float du = dvc*xvc;
    float a0 = exp2f(dvc*Av[0]), a1 = exp2f(dvc*Av[1]),
          a2 = exp2f(dvc*Av[2]), a3 = exp2f(dvc*Av[3]);
    h[0] = h[0]*a0 + du*Bvc.x; ap[0] *= a0;
    h[1] = h[1]*a1 + du*Bvc.y; ap[1] *= a1;
    h[2] = h[2]*a2 + du*Bvc.z; ap[2] *= a2;
    h[3] = h[3]*a3 + du*Bvc.w; ap[3] *= a3;
    dvc = dvn; xvc = xvn; Bvc = Bvn;
  }
  size_t base = (size_t)chunk*NCH + (size_t)(b4k*DD + d)*NS + ng*4;
  *(float4*)&Ac[base] = make_float4(ap[0],ap[1],ap[2],ap[3]);
  *(float4*)&Bc[base] = make_float4(h[0],h[1],h[2],h[3]);
}

// K5b: sequential prefix over chunk summaries; writes incoming state IN-PLACE over Ac.
__global__ void k_scan2(float* __restrict__ Ac, const float* __restrict__ Bc){
  int chain = blockIdx.x*256 + threadIdx.x;
  float h = 0.f;
  for (int c = 0; c < NC; ++c){
    size_t idx = (size_t)c*NCH + chain;
    float a = Ac[idx], bv = Bc[idx];
    Ac[idx] = h;
    h = a*h + bv;
  }
}

// K5c: re-run chunks with correct h0 (hst == Ac buffer), emit ys. exp2f path.
__global__ void k_scan3(const float* __restrict__ dlt, const float* __restrict__ xc,
                        const float* __restrict__ Bsb, const float* __restrict__ Csb,
                        const float* __restrict__ Alog, const float* __restrict__ hst,
                        float* __restrict__ ys){
  int tid = blockIdx.x*256 + threadIdx.x;
  int ng = tid & 3;
  int t2 = tid >> 2;
  int d = t2 % DD;
  int rest = t2 / DD;
  int chunk = rest & (NC-1);
  int b4k = rest >> 6;
  int k = b4k & 3, b = b4k >> 2;
  float4 Af = *(const float4*)&Alog[(size_t)(k*DD+d)*NS + ng*4];
  float Av[4] = {-__expf(Af.x)*LOG2E, -__expf(Af.y)*LOG2E,
                 -__expf(Af.z)*LOG2E, -__expf(Af.w)*LOG2E};
  size_t hbase = (size_t)chunk*NCH + (size_t)(b4k*DD + d)*NS + ng*4;
  float4 hf = *(const float4*)&hst[hbase];
  float h[4] = {hf.x, hf.y, hf.z, hf.w};
  int l0 = chunk*LC;
  const float* dp  = dlt + ((size_t)b4k*HW + l0)*DD + d;
  const float4* Bp4 = (const float4*)(Bsb + ((size_t)b4k*HW + l0)*NS) + ng;
  const float4* Cp4 = (const float4*)(Csb + ((size_t)b4k*HW + l0)*NS) + ng;
  const float* xcb = xc + (size_t)b*HW*DD + d;
  float* yp = ys + ((size_t)b4k*HW + l0)*DD + d;
  float dvc = dp[0];
  float xvc = xcb[(size_t)lmap_xs(k, l0)*DD];
  float4 Bvc = Bp4[0];
  float4 Cvc = Cp4[0];
  #pragma unroll 4
  for (int i = 0; i < LC; ++i){
    float dvn = 0.f, xvn = 0.f; float4 Bvn = {0.f,0.f,0.f,0.f}, Cvn = {0.f,0.f,0.f,0.f};
    if (i+1 < LC){
      dvn = dp[(size_t)(i+1)*DD];
      xvn = xcb[(size_t)lmap_xs(k, l0+i+1)*DD];
      Bvn = Bp4[(size_t)(i+1)*4];
      Cvn = Cp4[(size_t)(i+1)*4];
    }
    float du = dvc*xvc;
    float a0 = exp2f(dvc*Av[0]), a1 = exp2f(dvc*Av[1]),
          a2 = exp2f(dvc*Av[2]), a3 = exp2f(dvc*Av[3]);
    h[0] = h[0]*a0 + du*Bvc.x;
    h[1] = h[1]*a1 + du*Bvc.y;
    h[2] = h[2]*a2 + du*Bvc.z;
    h[3] = h[3]*a3 + du*Bvc.w;
    float y = h[0]*Cvc.x + h[1]*Cvc.y + h[2]*Cvc.z + h[3]*Cvc.w;
    y += __shfl_xor(y, 1, 4);
    y += __shfl_xor(y, 2, 4);
    if (ng == 0) yp[(size_t)i*DD] = y;
    dvc = dvn; xvc = xvn; Bvc = Bvn; Cvc = Cvn;
  }
}

// K6a: merge 4 dirs + D*xs skip, LN over 192, *silu(z) -> yg (B,L,192). Wave per pixel.
__global__ void k_gate(const float* __restrict__ ys, const float* __restrict__ xc,
                       const float* __restrict__ Ds, const float* __restrict__ xz,
                       const float* __restrict__ ong, const float* __restrict__ onb,
                       float* __restrict__ yg){
  int gt = blockIdx.x*256 + threadIdx.x;
  int wave = gt >> 6;
  int lane = gt & 63;
  int b = wave >> 12; int l = wave & (HW-1);
  int l1 = ((l & 63) << 6) | (l >> 6);
  size_t base = (size_t)b*KK*HW*DD;
  float v[3]; float s = 0.f, s2 = 0.f;
  #pragma unroll
  for (int j = 0; j < 3; ++j){
    int d = lane + j*64;
    float t;
    t  = ys[base + ((size_t)0*HW + l        )*DD + d];
    t += ys[base + ((size_t)1*HW + l1       )*DD + d];
    t += ys[base + ((size_t)2*HW + (HW-1-l ))*DD + d];
    t += ys[base + ((size_t)3*HW + (HW-1-l1))*DD + d];
    t += xc[((size_t)b*HW + l)*DD + d] * (Ds[d] + Ds[DD+d] + Ds[2*DD+d] + Ds[3*DD+d]);
    v[j] = t; s += t; s2 += t*t;
  }
  #pragma unroll
  for (int off = 32; off; off >>= 1){ s += __shfl_xor(s, off); s2 += __shfl_xor(s2, off); }
  float mu = s*(1.f/DD);
  float rstd = rsqrtf(s2*(1.f/DD) - mu*mu + 1e-5f);
  #pragma unroll
  for (int j = 0; j < 3; ++j){
    int d = lane + j*64;
    float z = xz[((size_t)b*HW + l)*384 + DD + d];
    float x = (v[j]-mu)*rstd*ong[d] + onb[d];
    yg[(size_t)wave*DD + d] = x * siluf(z);
  }
}

// K6b: out = yg(8192x192) @ opw^T(192x96), NCHW write. 32px x 96c per block.
__global__ void k_outproj(const float* __restrict__ yg, const float* __restrict__ opw,
                          float* __restrict__ out){
  __shared__ float yl[48][36];
  __shared__ float wl[48][97];
  int blk = blockIdx.x;
  int b = blk >> 7; int pt = blk & 127;
  int px0 = pt*32;
  int tid = threadIdx.x;
  int pxg = tid & 7;
  int cgi = tid >> 3;
  float acc[4][3] = {};
  for (int k0 = 0; k0 < DD; k0 += 48){
    if (k0) __syncthreads();
    for (int i = tid; i < 32*48; i += 256){
      int r = i/48, k = i - r*48;
      yl[k][r] = yg[((size_t)b*HW + px0 + r)*DD + k0 + k];
    }
    for (int i = tid; i < 96*48; i += 256){
      int c = i/48, k = i - c*48;
      wl[k][c] = opw[(size_t)c*DD + k0 + k];
    }
    __syncthreads();
    #pragma unroll 4
    for (int k = 0; k < 48; ++k){
      float4 yv = *(const float4*)&yl[k][pxg*4];
      float w0 = wl[k][cgi*3], w1 = wl[k][cgi*3+1], w2 = wl[k][cgi*3+2];
      acc[0][0] += yv.x*w0; acc[0][1] += yv.x*w1; acc[0][2] += yv.x*w2;
      acc[1][0] += yv.y*w0; acc[1][1] += yv.y*w1; acc[1][2] += yv.y*w2;
      acc[2][0] += yv.z*w0; acc[2][1] += yv.z*w1; acc[2][2] += yv.z*w2;
      acc[3][0] += yv.w*w0; acc[3][1] += yv.w*w1; acc[3][2] += yv.w*w2;
    }
  }
  #pragma unroll
  for (int j = 0; j < 3; ++j){
    int c = cgi*3 + j;
    float4 o = {acc[0][j], acc[1][j], acc[2][j], acc[3][j]};
    *(float4*)&out[((size_t)b*CC + c)*HW + px0 + pxg*4] = o;
  }
}

extern "C" void kernel_launch(void* const* d_in, const int* in_sizes, int n_in,
                              void* d_out, int out_size, void* d_ws, size_t ws_size,
                              hipStream_t stream) {
  const float* rgb   = (const float*)d_in[0];
  const float* tt    = (const float*)d_in[1];
  const float* cw    = (const float*)d_in[2];
  const float* cb    = (const float*)d_in[3];
  const float* bng   = (const float*)d_in[4];
  const float* bnb   = (const float*)d_in[5];
  const float* bnm   = (const float*)d_in[6];
  const float* bnv   = (const float*)d_in[7];
  const float* lng   = (const float*)d_in[8];
  const float* lnb   = (const float*)d_in[9];
  const float* ipw   = (const float*)d_in[10];
  const float* dww   = (const float*)d_in[11];
  const float* dwb   = (const float*)d_in[12];
  const float* xpw   = (const float*)d_in[13];
  const float* dtw   = (const float*)d_in[14];
  const float* dtb   = (const float*)d_in[15];
  const float* Alog  = (const float*)d_in[16];
  const float* Ds    = (const float*)d_in[17];
  const float* ong   = (const float*)d_in[18];
  const float* onb   = (const float*)d_in[19];
  const float* opw   = (const float*)d_in[20];
  float* out = (float*)d_out;

  float* ws = (float*)d_ws;
  // persistent regions (floats):
  float* xn   = ws + 786432;                 // 786432 (pixel-major, post-LN)
  float* xz   = ws + 1572864;                // 3145728
  float* xc   = ws + 4718592;                // 1572864
  float* Bsb  = ws + 6291456;                // 524288
  float* Csb  = ws + 6815744;                // 524288
  float* dlt  = ws + 7340032;                // 6291456
  float* ysb  = ws + 13631488;               // 6291456 (end 19922944 ~79.7MB)
  // transient overlays:
  float* pbuf = ws + 1572864;                // 12582912 (16 partials; dead pre-inproj)
  float* Ac   = ws;                          // 1572864 (xn region; dead by scan1)
  float* Bc   = ysb;                         // 1572864 (front of ysb; dead before scan3 writes ys)
  float* yg   = ws + 7340032;                // 1572864 (over dlt; dlt dead after scan3)
  float* wT   = ws + 16777216;               // 165888 (ysb tail; consumed by conv1 before scan3)
  float* xpwT = ws + 16943104;               // 29184 (consumed by xdbl before scan3)
  // k_scan2 writes hst in-place over Ac; k_scan3 reads it from there.

  k_prep<<<762, 256, 0, stream>>>(cw, xpw, wT, xpwT);
  k_conv1<<<1024, 256, 0, stream>>>(rgb, tt, wT, pbuf);
  k_convred<<<4096, 256, 0, stream>>>(pbuf, cb, bng, bnb, bnm, bnv, lng, lnb, xn);
  dim3 g2(128, 6);
  k_inproj<<<g2, 256, 0, stream>>>(xn, ipw, xz);
  k_dwconv<<<1536, 256, 0, stream>>>(xz, dww, dwb, xc);
  k_xdbl<<<1024, 320, 0, stream>>>(xc, xpwT, dtw, dtb, Bsb, Csb, dlt);
  k_scan1<<<1536, 256, 0, stream>>>(dlt, xc, Bsb, Alog, Ac, Bc);
  k_scan2<<<96, 256, 0, stream>>>(Ac, Bc);
  k_scan3<<<1536, 256, 0, stream>>>(dlt, xc, Bsb, Csb, Alog, Ac, ysb);
  k_gate<<<2048, 256, 0, stream>>>(ysb, xc, Ds, xz, ong, onb, yg);
  k_outproj<<<256, 256, 0, stream>>>(yg, opw, out);
}

// Round 21
// 232.654 us; speedup vs baseline: 1.0632x; 1.0632x over previous
//
#include <hip/hip_runtime.h>
#include <math.h>

#define HW 4096
#define CC 96
#define DD 192
#define NS 16
#define KK 4
#define LC 64
#define NC 64
#define NCH (8*DD*NS)   // 24576 chains

__device__ __forceinline__ float siluf(float x){ return x / (1.f + __expf(-x)); }
__device__ __forceinline__ float softplus_fast(float x){ return (x > 20.f) ? x : __logf(1.f + __expf(x)); }

__device__ __forceinline__ int lmap_xs(int k, int l){
  if (k == 1) return ((l & 63) << 6) | (l >> 6);
  if (k == 2) return (HW - 1) - l;
  if (k == 3) { int r = (HW - 1) - l; return ((r & 63) << 6) | (r >> 6); }
  return l;
}

// K0: merged weight pre-transposes.
__global__ void k_prep(const float* __restrict__ cw, const float* __restrict__ xpw,
                       float* __restrict__ wT, float* __restrict__ xpwT){
  int o = blockIdx.x*256 + threadIdx.x;
  if (o < 165888){
    int co = o % 96; int rest = o / 96; int tap = rest % 9; int cig = rest / 9;
    wT[o] = cw[((size_t)co*192 + cig)*9 + tap];
  } else if (o < 165888 + 29184){
    int o2 = o - 165888;
    int c = o2 % 38; int rest = o2 / 38; int d = rest % 192; int k = rest / 192;
    xpwT[o2] = xpw[((size_t)(k*38 + c))*192 + d];
  }
}

// K1 v4 (best verified): conv3x3(192->96) partials, K-split 16 x 12ci.
__global__ void __launch_bounds__(256, 4)
k_conv1(const float* __restrict__ rgb, const float* __restrict__ tt,
        const float* __restrict__ wT, float* __restrict__ pbuf){
  __shared__ float in_lds[6][6][68];
  __shared__ __align__(16) float w_lds[6][9][64];
  int bi = blockIdx.x;
  int kc  = bi & 15;        int ci0 = kc*12;
  int cog = (bi >> 4) & 1;  int co0 = cog*48;
  int b   = (bi >> 5) & 1;
  int pt  = bi >> 6;        int h0 = pt*4;
  int tid = threadIdx.x;
  int pg = tid & 31;  int r = pg >> 3;  int w0 = (pg & 7)*8;
  int cg = tid >> 5;  int co_t = cg*6;

  float acc[6][8];
  #pragma unroll
  for (int c = 0; c < 6; ++c)
    #pragma unroll
    for (int p = 0; p < 8; ++p) acc[c][p] = 0.f;

  for (int s = 0; s < 2; ++s){
    if (s) __syncthreads();
    if (tid < 72){ int side = tid & 1; int rr = (tid % 12) >> 1; int ci = tid / 12;
                   in_lds[ci][rr][side ? 65 : 0] = 0.f; }
    for (int i = tid; i < 2304; i += 256){
      int ci = i / 384; int rem = i - ci*384; int rr = rem >> 6; int w = rem & 63;
      int grow = h0 - 1 + rr;
      int cig = ci0 + s*6 + ci;
      float v = 0.f;
      if (grow >= 0 && grow < 64){
        const float* src = (cig < CC) ? (rgb + (size_t)(b*CC+cig)*HW)
                                      : (tt  + (size_t)(b*CC+cig-CC)*HW);
        v = src[grow*64 + w];
      }
      in_lds[ci][rr][w+1] = v;
    }
    for (int i = tid; i < 2592; i += 256){
      int co = i % 48; int rest = i / 48; int tap = rest % 9; int ci = rest / 9;
      w_lds[ci][tap][(co/6)*8 + (co%6)] =
          wT[((size_t)(ci0 + s*6 + ci)*9 + tap)*96 + co0 + co];
    }
    __syncthreads();
    #pragma unroll
    for (int ci = 0; ci < 6; ++ci){
      float rowv[3][10];
      #pragma unroll
      for (int rr = 0; rr < 3; ++rr){
        const float* rp = &in_lds[ci][r+rr][w0];
        float4 a = *(const float4*)rp;
        float4 bb = *(const float4*)(rp+4);
        float2 cc = *(const float2*)(rp+8);
        rowv[rr][0]=a.x; rowv[rr][1]=a.y; rowv[rr][2]=a.z; rowv[rr][3]=a.w;
        rowv[rr][4]=bb.x; rowv[rr][5]=bb.y; rowv[rr][6]=bb.z; rowv[rr][7]=bb.w;
        rowv[rr][8]=cc.x; rowv[rr][9]=cc.y;
      }
      #pragma unroll
      for (int tap = 0; tap < 9; ++tap){
        int rt = tap/3, ct = tap - rt*3;
        float4 wa = *(const float4*)&w_lds[ci][tap][cg*8];
        float2 wb = *(const float2*)&w_lds[ci][tap][cg*8+4];
        float wv[6] = {wa.x, wa.y, wa.z, wa.w, wb.x, wb.y};
        #pragma unroll
        for (int p = 0; p < 8; ++p){
          float iv = rowv[rt][p + ct];
          #pragma unroll
          for (int c = 0; c < 6; ++c) acc[c][p] += wv[c]*iv;
        }
      }
    }
  }
  #pragma unroll
  for (int p = 0; p < 8; ++p){
    int pix = (h0 + r)*64 + w0 + p;
    float* o = pbuf + (((size_t)kc*2 + b)*HW + pix)*CC + co0 + co_t;
    float2 o0 = {acc[0][p], acc[1][p]};
    float2 o1 = {acc[2][p], acc[3][p]};
    float2 o2 = {acc[4][p], acc[5][p]};
    *(float2*)&o[0] = o0; *(float2*)&o[2] = o1; *(float2*)&o[4] = o2;
  }
}

// K1b: reduce 16 partials + bias + BN + ReLU + per-pixel LayerNorm -> xn (pixel-major)
__global__ void k_convred(const float* __restrict__ pbuf, const float* __restrict__ cb,
                          const float* __restrict__ bng, const float* __restrict__ bnb,
                          const float* __restrict__ bnm, const float* __restrict__ bnv,
                          const float* __restrict__ lng, const float* __restrict__ lnb,
                          float* __restrict__ xn){
  __shared__ float sm[4], sm2[4], smu[2], srs[2];
  int tid = threadIdx.x;
  int half = tid >> 7;
  int c = tid & 127;
  int pixg = blockIdx.x*2 + half;
  int b = pixg >> 12; int pix = pixg & (HW-1);
  float v = 0.f;
  if (c < CC){
    #pragma unroll
    for (int kc = 0; kc < 16; ++kc)
      v += pbuf[(((size_t)kc*2 + b)*HW + pix)*CC + c];
    v += cb[c];
    v = (v - bnm[c]) * rsqrtf(bnv[c] + 1e-5f);
    v = v * bng[c] + bnb[c];
    v = fmaxf(v, 0.f);
  }
  float s = v, s2 = v*v;
  #pragma unroll
  for (int off = 32; off; off >>= 1){ s += __shfl_down(s, off); s2 += __shfl_down(s2, off); }
  if ((tid & 63) == 0){ sm[tid>>6] = s; sm2[tid>>6] = s2; }
  __syncthreads();
  if (tid < 2){
    float ts = sm[2*tid] + sm[2*tid+1];
    float ts2 = sm2[2*tid] + sm2[2*tid+1];
    float mu = ts * (1.f/CC);
    float var = ts2 * (1.f/CC) - mu*mu;
    smu[tid] = mu; srs[tid] = rsqrtf(var + 1e-5f);
  }
  __syncthreads();
  if (c < CC)
    xn[(size_t)pixg*CC + c] = (v - smu[half])*srs[half]*lng[c] + lnb[c];
}

// K2b: xz(8192x384) = xn(8192x96) @ in_proj_w^T(96x384)
__global__ void k_inproj(const float* __restrict__ xn, const float* __restrict__ ipw,
                         float* __restrict__ xz){
  __shared__ float As[64][97];
  __shared__ __align__(16) float Bs[96][68];
  int p0 = blockIdx.x*64;
  int e0 = blockIdx.y*64;
  int tid = threadIdx.x;
  for (int idx = tid; idx < 64*96; idx += 256){
    int r = idx/96, c = idx - r*96;
    As[r][c] = xn[(size_t)(p0+r)*96 + c];
  }
  for (int idx = tid; idx < 96*64; idx += 256){
    int c = idx/64, e = idx - c*64;
    Bs[c][e] = ipw[(size_t)(e0+e)*96 + c];
  }
  __syncthreads();
  int tx = tid & 15, ty = tid >> 4;
  float acc[4][4] = {};
  for (int c = 0; c < 96; ++c){
    float a[4];
    #pragma unroll
    for (int i = 0; i < 4; ++i) a[i] = As[ty*4+i][c];
    float4 bb = *(const float4*)&Bs[c][tx*4];
    float bv[4] = {bb.x, bb.y, bb.z, bb.w};
    #pragma unroll
    for (int i = 0; i < 4; ++i)
      #pragma unroll
      for (int j = 0; j < 4; ++j) acc[i][j] += a[i]*bv[j];
  }
  for (int i = 0; i < 4; ++i){
    float4 o = {acc[i][0], acc[i][1], acc[i][2], acc[i][3]};
    *(float4*)&xz[(size_t)(p0+ty*4+i)*384 + e0 + tx*4] = o;
  }
}

// K3 v2: depthwise 3x3 conv + bias + SiLU -> xc (B, L, 192). Thread = 4 consecutive d.
__global__ void k_dwconv(const float* __restrict__ xz, const float* __restrict__ dww,
                         const float* __restrict__ dwb, float* __restrict__ xc){
  int gid = blockIdx.x*256 + threadIdx.x;    // 8192*48
  int dq = gid % 48; int bp = gid / 48;
  int d = dq*4;
  int pix = bp & (HW-1); int b = bp >> 12;
  int h = pix >> 6, w = pix & 63;
  float4 acc = *(const float4*)&dwb[d];
  float wreg[4][9];
  #pragma unroll
  for (int j = 0; j < 4; ++j)
    #pragma unroll
    for (int t = 0; t < 9; ++t) wreg[j][t] = dww[(d+j)*9 + t];
  #pragma unroll
  for (int dh = -1; dh <= 1; ++dh){
    int hh = h + dh;
    if (hh < 0 || hh > 63) continue;
    #pragma unroll
    for (int dw2 = -1; dw2 <= 1; ++dw2){
      int ww = w + dw2;
      if (ww < 0 || ww > 63) continue;
      float4 v = *(const float4*)&xz[((size_t)b*HW + hh*64 + ww)*384 + d];
      int t = (dh+1)*3 + (dw2+1);
      acc.x += v.x*wreg[0][t];
      acc.y += v.y*wreg[1][t];
      acc.z += v.z*wreg[2][t];
      acc.w += v.w*wreg[3][t];
    }
  }
  float4 o = {siluf(acc.x), siluf(acc.y), siluf(acc.z), siluf(acc.w)};
  *(float4*)&xc[(size_t)bp*DD + d] = o;
}

// K4 v6: x_dbl for a DIRECTION PAIR per block, 16-px tiles (1024 blocks).
// Fused delta epilogue. No idiv in staging loops.
__global__ void __launch_bounds__(320)
k_xdbl(const float* __restrict__ xc, const float* __restrict__ xpwT,
       const float* __restrict__ dtw, const float* __restrict__ dtb,
       float* __restrict__ Bsb, float* __restrict__ Csb, float* __restrict__ dlt){
  __shared__ float xs_t[48*20];      // [dd][j], 16 j + 4 pad
  __shared__ float w_t[48*80];       // [dd][c]: c<38 -> k=p, c>=38 -> k=p+2
  __shared__ float dts_s[2][16][8];
  int blk = blockIdx.x;              // b*512 + p*256 + lt
  int lt = blk & 255; int p = (blk >> 8) & 1; int b = blk >> 9;
  int l0 = lt*16;
  int tid = threadIdx.x;
  int lg = tid & 15, cg = tid >> 4;  // cg 0..19
  int c0 = cg*4;
  int b4kA = b*4 + p, b4kB = b*4 + p + 2;
  int wc = tid % 76;
  int wg = tid / 76;
  int kkW = (wc < 38) ? p : (p + 2);
  int ccW = (wc < 38) ? wc : wc - 38;

  float acc[4] = {0.f, 0.f, 0.f, 0.f};
  for (int ch = 0; ch < 4; ++ch){
    int d0 = ch*48;
    if (ch) __syncthreads();
    if (tid < 192){
      int j = tid & 15; int dq = tid >> 4;
      int l = l0 + j;
      int lm = (p == 0) ? l : (((l & 63) << 6) | (l >> 6));
      float4 v = *(const float4*)&xc[((size_t)b*HW + lm)*DD + d0 + dq*4];
      xs_t[(dq*4+0)*20 + j] = v.x;
      xs_t[(dq*4+1)*20 + j] = v.y;
      xs_t[(dq*4+2)*20 + j] = v.z;
      xs_t[(dq*4+3)*20 + j] = v.w;
    }
    if (wg < 4){
      #pragma unroll
      for (int dd = wg; dd < 48; dd += 4)
        w_t[dd*80 + wc] = xpwT[((size_t)kkW*192 + d0 + dd)*38 + ccW];
    }
    __syncthreads();
    #pragma unroll 4
    for (int dd = 0; dd < 48; ++dd){
      float4 wv = *(const float4*)&w_t[dd*80 + c0];
      float xv = xs_t[dd*20 + lg];
      acc[0] += wv.x*xv;
      acc[1] += wv.y*xv;
      acc[2] += wv.z*xv;
      acc[3] += wv.w*xv;
    }
  }
  {
    int lf = l0 + lg;
    int lr = HW - 1 - lf;
    #pragma unroll
    for (int j = 0; j < 4; ++j){
      int c = c0 + j;
      float v = acc[j];
      if      (c <  6) dts_s[0][lg][c] = v;
      else if (c < 22) Bsb [((size_t)b4kA*HW + lf)*NS + (c-6)]   = v;
      else if (c < 38) Csb [((size_t)b4kA*HW + lf)*NS + (c-22)]  = v;
      else if (c < 44) dts_s[1][lg][c-38] = v;
      else if (c < 60) Bsb [((size_t)b4kB*HW + lr)*NS + (c-44)]  = v;
      else if (c < 76) Csb [((size_t)b4kB*HW + lr)*NS + (c-60)]  = v;
    }
  }
  __syncthreads();

  for (int o = tid; o < 6144; o += 320){
    int dir = (o >= 3072) ? 1 : 0;
    int oo = o - dir*3072;
    int lj = oo / 192;
    int d  = oo - lj*192;
    int k  = dir ? (p + 2) : p;
    int b4k = dir ? b4kB : b4kA;
    int lout = dir ? (HW - 1 - (l0 + lj)) : (l0 + lj);
    const float* t = dts_s[dir][lj];
    const float* wp = &dtw[(size_t)(k*DD + d)*6];
    float s = dtb[k*DD + d] + t[0]*wp[0] + t[1]*wp[1] + t[2]*wp[2]
                            + t[3]*wp[3] + t[4]*wp[4] + t[5]*wp[5];
    dlt[((size_t)b4k*HW + lout)*DD + d] = softplus_fast(s);
  }
}

// K5a (4-lane, verified): per-chunk scan summaries. Thread owns 4 states.
__global__ void k_scan1(const float* __restrict__ dlt, const float* __restrict__ xc,
                        const float* __restrict__ Bsb, const float* __restrict__ Alog,
                        float* __restrict__ Ac, float* __restrict__ Bc){
  int tid = blockIdx.x*256 + threadIdx.x;
  int ng = tid & 3;
  int t2 = tid >> 2;
  int d = t2 % DD;
  int rest = t2 / DD;
  int chunk = rest & (NC-1);
  int b4k = rest >> 6;
  int k = b4k & 3, b = b4k >> 2;
  float4 Af = *(const float4*)&Alog[(size_t)(k*DD+d)*NS + ng*4];
  float Av[4] = {-__expf(Af.x), -__expf(Af.y), -__expf(Af.z), -__expf(Af.w)};
  float h[4] = {0.f,0.f,0.f,0.f};
  float ap[4] = {1.f,1.f,1.f,1.f};
  int l0 = chunk*LC;
  const float* dp  = dlt + ((size_t)b4k*HW + l0)*DD + d;
  const float4* Bp4 = (const float4*)(Bsb + ((size_t)b4k*HW + l0)*NS) + ng;
  const float* xcb = xc + (size_t)b*HW*DD + d;
  float dvc = dp[0];
  float xvc = xcb[(size_t)lmap_xs(k, l0)*DD];
  float4 Bvc = Bp4[0];
  #pragma unroll 4
  for (int i = 0; i < LC; ++i){
    float dvn = 0.f, xvn = 0.f; float4 Bvn = {0.f,0.f,0.f,0.f};
    if (i+1 < LC){
      dvn = dp[(size_t)(i+1)*DD];
      xvn = xcb[(size_t)lmap_xs(k, l0+i+1)*DD];
      Bvn = Bp4[(size_t)(i+1)*4];
    }
    float du = dvc*xvc;
    float a0 = __expf(dvc*Av[0]), a1 = __expf(dvc*Av[1]),
          a2 = __expf(dvc*Av[2]), a3 = __expf(dvc*Av[3]);
    h[0] = h[0]*a0 + du*Bvc.x; ap[0] *= a0;
    h[1] = h[1]*a1 + du*Bvc.y; ap[1] *= a1;
    h[2] = h[2]*a2 + du*Bvc.z; ap[2] *= a2;
    h[3] = h[3]*a3 + du*Bvc.w; ap[3] *= a3;
    dvc = dvn; xvc = xvn; Bvc = Bvn;
  }
  size_t base = (size_t)chunk*NCH + (size_t)(b4k*DD + d)*NS + ng*4;
  *(float4*)&Ac[base] = make_float4(ap[0],ap[1],ap[2],ap[3]);
  *(float4*)&Bc[base] = make_float4(h[0],h[1],h[2],h[3]);
}

// K5b: sequential prefix over chunk summaries; writes incoming state IN-PLACE over Ac.
__global__ void k_scan2(float* __restrict__ Ac, const float* __restrict__ Bc){
  int chain = blockIdx.x*256 + threadIdx.x;
  float h = 0.f;
  for (int c = 0; c < NC; ++c){
    size_t idx = (size_t)c*NCH + chain;
    float a = Ac[idx], bv = Bc[idx];
    Ac[idx] = h;
    h = a*h + bv;
  }
}

// K5c (4-lane, verified): re-run chunks with correct h0, emit ys.
__global__ void k_scan3(const float* __restrict__ dlt, const float* __restrict__ xc,
                        const float* __restrict__ Bsb, const float* __restrict__ Csb,
                        const float* __restrict__ Alog, const float* __restrict__ hst,
                        float* __restrict__ ys){
  int tid = blockIdx.x*256 + threadIdx.x;
  int ng = tid & 3;
  int t2 = tid >> 2;
  int d = t2 % DD;
  int rest = t2 / DD;
  int chunk = rest & (NC-1);
  int b4k = rest >> 6;
  int k = b4k & 3, b = b4k >> 2;
  float4 Af = *(const float4*)&Alog[(size_t)(k*DD+d)*NS + ng*4];
  float Av[4] = {-__expf(Af.x), -__expf(Af.y), -__expf(Af.z), -__expf(Af.w)};
  size_t hbase = (size_t)chunk*NCH + (size_t)(b4k*DD + d)*NS + ng*4;
  float4 hf = *(const float4*)&hst[hbase];
  float h[4] = {hf.x, hf.y, hf.z, hf.w};
  int l0 = chunk*LC;
  const float* dp  = dlt + ((size_t)b4k*HW + l0)*DD + d;
  const float4* Bp4 = (const float4*)(Bsb + ((size_t)b4k*HW + l0)*NS) + ng;
  const float4* Cp4 = (const float4*)(Csb + ((size_t)b4k*HW + l0)*NS) + ng;
  const float* xcb = xc + (size_t)b*HW*DD + d;
  float* yp = ys + ((size_t)b4k*HW + l0)*DD + d;
  float dvc = dp[0];
  float xvc = xcb[(size_t)lmap_xs(k, l0)*DD];
  float4 Bvc = Bp4[0];
  float4 Cvc = Cp4[0];
  #pragma unroll 4
  for (int i = 0; i < LC; ++i){
    float dvn = 0.f, xvn = 0.f; float4 Bvn = {0.f,0.f,0.f,0.f}, Cvn = {0.f,0.f,0.f,0.f};
    if (i+1 < LC){
      dvn = dp[(size_t)(i+1)*DD];
      xvn = xcb[(size_t)lmap_xs(k, l0+i+1)*DD];
      Bvn = Bp4[(size_t)(i+1)*4];
      Cvn = Cp4[(size_t)(i+1)*4];
    }
    float du = dvc*xvc;
    float a0 = __expf(dvc*Av[0]), a1 = __expf(dvc*Av[1]),
          a2 = __expf(dvc*Av[2]), a3 = __expf(dvc*Av[3]);
    h[0] = h[0]*a0 + du*Bvc.x;
    h[1] = h[1]*a1 + du*Bvc.y;
    h[2] = h[2]*a2 + du*Bvc.z;
    h[3] = h[3]*a3 + du*Bvc.w;
    float y = h[0]*Cvc.x + h[1]*Cvc.y + h[2]*Cvc.z + h[3]*Cvc.w;
    y += __shfl_xor(y, 1, 4);
    y += __shfl_xor(y, 2, 4);
    if (ng == 0) yp[(size_t)i*DD] = y;
    dvc = dvn; xvc = xvn; Bvc = Bvn; Cvc = Cvn;
  }
}

// K6a: merge 4 dirs + D*xs skip, LN over 192, *silu(z) -> yg (B,L,192). Wave per pixel.
__global__ void k_gate(const float* __restrict__ ys, const float* __restrict__ xc,
                       const float* __restrict__ Ds, const float* __restrict__ xz,
                       const float* __restrict__ ong, const float* __restrict__ onb,
                       float* __restrict__ yg){
  int gt = blockIdx.x*256 + threadIdx.x;
  int wave = gt >> 6;
  int lane = gt & 63;
  int b = wave >> 12; int l = wave & (HW-1);
  int l1 = ((l & 63) << 6) | (l >> 6);
  size_t base = (size_t)b*KK*HW*DD;
  float v[3]; float s = 0.f, s2 = 0.f;
  #pragma unroll
  for (int j = 0; j < 3; ++j){
    int d = lane + j*64;
    float t;
    t  = ys[base + ((size_t)0*HW + l        )*DD + d];
    t += ys[base + ((size_t)1*HW + l1       )*DD + d];
    t += ys[base + ((size_t)2*HW + (HW-1-l ))*DD + d];
    t += ys[base + ((size_t)3*HW + (HW-1-l1))*DD + d];
    t += xc[((size_t)b*HW + l)*DD + d] * (Ds[d] + Ds[DD+d] + Ds[2*DD+d] + Ds[3*DD+d]);
    v[j] = t; s += t; s2 += t*t;
  }
  #pragma unroll
  for (int off = 32; off; off >>= 1){ s += __shfl_xor(s, off); s2 += __shfl_xor(s2, off); }
  float mu = s*(1.f/DD);
  float rstd = rsqrtf(s2*(1.f/DD) - mu*mu + 1e-5f);
  #pragma unroll
  for (int j = 0; j < 3; ++j){
    int d = lane + j*64;
    float z = xz[((size_t)b*HW + l)*384 + DD + d];
    float x = (v[j]-mu)*rstd*ong[d] + onb[d];
    yg[(size_t)wave*DD + d] = x * siluf(z);
  }
}

// K6b: out = yg(8192x192) @ opw^T(192x96), NCHW write. 32px x 96c per block.
__global__ void k_outproj(const float* __restrict__ yg, const float* __restrict__ opw,
                          float* __restrict__ out){
  __shared__ float yl[48][36];
  __shared__ float wl[48][97];
  int blk = blockIdx.x;
  int b = blk >> 7; int pt = blk & 127;
  int px0 = pt*32;
  int tid = threadIdx.x;
  int pxg = tid & 7;
  int cgi = tid >> 3;
  float acc[4][3] = {};
  for (int k0 = 0; k0 < DD; k0 += 48){
    if (k0) __syncthreads();
    for (int i = tid; i < 32*48; i += 256){
      int r = i/48, k = i - r*48;
      yl[k][r] = yg[((size_t)b*HW + px0 + r)*DD + k0 + k];
    }
    for (int i = tid; i < 96*48; i += 256){
      int c = i/48, k = i - c*48;
      wl[k][c] = opw[(size_t)c*DD + k0 + k];
    }
    __syncthreads();
    #pragma unroll 4
    for (int k = 0; k < 48; ++k){
      float4 yv = *(const float4*)&yl[k][pxg*4];
      float w0 = wl[k][cgi*3], w1 = wl[k][cgi*3+1], w2 = wl[k][cgi*3+2];
      acc[0][0] += yv.x*w0; acc[0][1] += yv.x*w1; acc[0][2] += yv.x*w2;
      acc[1][0] += yv.y*w0; acc[1][1] += yv.y*w1; acc[1][2] += yv.y*w2;
      acc[2][0] += yv.z*w0; acc[2][1] += yv.z*w1; acc[2][2] += yv.z*w2;
      acc[3][0] += yv.w*w0; acc[3][1] += yv.w*w1; acc[3][2] += yv.w*w2;
    }
  }
  #pragma unroll
  for (int j = 0; j < 3; ++j){
    int c = cgi*3 + j;
    float4 o = {acc[0][j], acc[1][j], acc[2][j], acc[3][j]};
    *(float4*)&out[((size_t)b*CC + c)*HW + px0 + pxg*4] = o;
  }
}

extern "C" void kernel_launch(void* const* d_in, const int* in_sizes, int n_in,
                              void* d_out, int out_size, void* d_ws, size_t ws_size,
                              hipStream_t stream) {
  const float* rgb   = (const float*)d_in[0];
  const float* tt    = (const float*)d_in[1];
  const float* cw    = (const float*)d_in[2];
  const float* cb    = (const float*)d_in[3];
  const float* bng   = (const float*)d_in[4];
  const float* bnb   = (const float*)d_in[5];
  const float* bnm   = (const float*)d_in[6];
  const float* bnv   = (const float*)d_in[7];
  const float* lng   = (const float*)d_in[8];
  const float* lnb   = (const float*)d_in[9];
  const float* ipw   = (const float*)d_in[10];
  const float* dww   = (const float*)d_in[11];
  const float* dwb   = (const float*)d_in[12];
  const float* xpw   = (const float*)d_in[13];
  const float* dtw   = (const float*)d_in[14];
  const float* dtb   = (const float*)d_in[15];
  const float* Alog  = (const float*)d_in[16];
  const float* Ds    = (const float*)d_in[17];
  const float* ong   = (const float*)d_in[18];
  const float* onb   = (const float*)d_in[19];
  const float* opw   = (const float*)d_in[20];
  float* out = (float*)d_out;

  float* ws = (float*)d_ws;
  // persistent regions (floats):
  float* xn   = ws + 786432;                 // 786432 (pixel-major, post-LN)
  float* xz   = ws + 1572864;                // 3145728
  float* xc   = ws + 4718592;                // 1572864
  float* Bsb  = ws + 6291456;                // 524288
  float* Csb  = ws + 6815744;                // 524288
  float* dlt  = ws + 7340032;                // 6291456
  float* ysb  = ws + 13631488;               // 6291456 (end 19922944 ~79.7MB)
  // transient overlays:
  float* pbuf = ws + 1572864;                // 12582912 (16 partials; dead pre-inproj)
  float* Ac   = ws;                          // 1572864 (xn region; dead by scan1)
  float* Bc   = ysb;                         // 1572864 (front of ysb; dead before scan3 writes ys)
  float* yg   = ws + 7340032;                // 1572864 (over dlt; dlt dead after scan3)
  float* wT   = ws + 16777216;               // 165888 (ysb tail; consumed by conv1 before scan3)
  float* xpwT = ws + 16943104;               // 29184 (consumed by xdbl before scan3)
  // k_scan2 writes hst in-place over Ac; k_scan3 reads it from there.

  k_prep<<<762, 256, 0, stream>>>(cw, xpw, wT, xpwT);
  k_conv1<<<1024, 256, 0, stream>>>(rgb, tt, wT, pbuf);
  k_convred<<<4096, 256, 0, stream>>>(pbuf, cb, bng, bnb, bnm, bnv, lng, lnb, xn);
  dim3 g2(128, 6);
  k_inproj<<<g2, 256, 0, stream>>>(xn, ipw, xz);
  k_dwconv<<<1536, 256, 0, stream>>>(xz, dww, dwb, xc);
  k_xdbl<<<1024, 320, 0, stream>>>(xc, xpwT, dtw, dtb, Bsb, Csb, dlt);
  k_scan1<<<1536, 256, 0, stream>>>(dlt, xc, Bsb, Alog, Ac, Bc);
  k_scan2<<<96, 256, 0, stream>>>(Ac, Bc);
  k_scan3<<<1536, 256, 0, stream>>>(dlt, xc, Bsb, Csb, Alog, Ac, ysb);
  k_gate<<<2048, 256, 0, stream>>>(ysb, xc, Ds, xz, ong, onb, yg);
  k_outproj<<<256, 256, 0, stream>>>(yg, opw, out);
}